// Round 3
// baseline (1831.252 us; speedup 1.0000x reference)
//
#include <hip/hip_runtime.h>
#include <hip/hip_bf16.h>
#include <math.h>

#define SEQ    1024
#define EMB    512
#define HID    512
#define G4     2048   // 4*HID
#define NSCAN  32     // scan blocks
#define NHELP  224    // helper blocks (xgates)
#define UPB    16     // hidden units per scan block
#define NSLOT  4      // rotating h slots (WAR-safe at distance 4)

typedef unsigned long long u64;

// One fused kernel. Blocks 0..31: persistent LSTM scan + attention head.
// Blocks 32..255: compute xg tiles (32 t x 64 r), publish per-32-t-chunk
// counters (release fence + agent atomicAdd), then exit.
__global__ __launch_bounds__(512) void fused_kernel(
    const int* __restrict__ tok, const float* __restrict__ emb,
    const float* __restrict__ w_ih, const float* __restrict__ w_hh,
    const float* __restrict__ b_ih, const float* __restrict__ b_hh,
    const float* __restrict__ attn_w, const float* __restrict__ attn_b,
    float* __restrict__ out,
    float* __restrict__ xg, u64* hslot, int* rdy32)
{
  __shared__ float xs[32][68];        // helper: x tile (+pad)
  __shared__ float wsh[64][68];       // helper: w_ih tile (+pad)
  __shared__ int   tok_s[32];
  __shared__ float h_lds[512];        // scan: h staging
  __shared__ float part_lds[2][512];  // scan: double-buffered partials
  __shared__ float redh[8];           // head reduction
  __shared__ float avals[2];

  const int tid = threadIdx.x;
  const int blk = blockIdx.x;

  // ========================= HELPERS: x_gates =========================
  if (blk >= NSCAN) {
    const int hb = blk - NSCAN;          // 0..223
    const int tx = tid & 31;             // r micro (2 each -> 64)
    const int ty = tid >> 5;             // t micro (2 each -> 32)
    for (int tau = hb; tau < 1024; tau += NHELP) {   // t-major tile order
      const int t0 = (tau >> 5) * 32;
      const int r0 = (tau & 31) * 64;
      if (tid < 32) tok_s[tid] = tok[t0 + tid];
      __syncthreads();

      float a00 = 0.f, a01 = 0.f, a10 = 0.f, a11 = 0.f;
      for (int kc = 0; kc < EMB; kc += 64) {
        {
          int row = tid >> 4, c4 = tid & 15;   // 512 slots, 1 pass
          *(float4*)&xs[row][c4 * 4] =
              *(const float4*)(emb + (size_t)tok_s[row] * EMB + kc + c4 * 4);
        }
#pragma unroll
        for (int it = 0; it < 2; ++it) {       // 1024 slots, 2 passes
          int id = it * 512 + tid;
          int row = id >> 4, c4 = id & 15;
          *(float4*)&wsh[row][c4 * 4] =
              *(const float4*)(w_ih + (size_t)(r0 + row) * EMB + kc + c4 * 4);
        }
        __syncthreads();
#pragma unroll
        for (int k4 = 0; k4 < 16; ++k4) {
          float4 x0 = *(const float4*)&xs[ty * 2 + 0][k4 * 4];
          float4 x1 = *(const float4*)&xs[ty * 2 + 1][k4 * 4];
          float4 w0 = *(const float4*)&wsh[tx * 2 + 0][k4 * 4];
          float4 w1 = *(const float4*)&wsh[tx * 2 + 1][k4 * 4];
          a00 += x0.x * w0.x + x0.y * w0.y + x0.z * w0.z + x0.w * w0.w;
          a01 += x0.x * w1.x + x0.y * w1.y + x0.z * w1.z + x0.w * w1.w;
          a10 += x1.x * w0.x + x1.y * w0.y + x1.z * w0.z + x1.w * w0.w;
          a11 += x1.x * w1.x + x1.y * w1.y + x1.z * w1.z + x1.w * w1.w;
        }
        __syncthreads();
      }
      const int rb = r0 + tx * 2;
      float b0 = b_ih[rb]     + b_hh[rb];
      float b1 = b_ih[rb + 1] + b_hh[rb + 1];
      float2 o0 = make_float2(a00 + b0, a01 + b1);
      float2 o1 = make_float2(a10 + b0, a11 + b1);
      *(float2*)(xg + (size_t)(t0 + ty * 2)     * G4 + rb) = o0;
      *(float2*)(xg + (size_t)(t0 + ty * 2 + 1) * G4 + rb) = o1;

      __threadfence();          // release tile stores to agent scope
      __syncthreads();
      if (tid == 0) atomicAdd(&rdy32[tau >> 5], 1);   // 32 tiles per chunk
    }
    return;
  }

  // =========================== SCAN BLOCKS ===========================
  const int w  = tid >> 6;            // wave id = k-segment
  const int l  = tid & 63;            // lane   = local gate row
  const int q  = l >> 4;              // gate type (i,f,g,o)
  const int jj = l & 15;              // local hidden unit
  const int grow = q * HID + blk * UPB + jj;  // global gate row

  // This thread's 64 w_hh weights -> VGPRs.
  float wreg[64];
  {
    const float* wp = w_hh + (size_t)grow * HID + w * 64;
#pragma unroll
    for (int k4 = 0; k4 < 16; ++k4) {
      float4 v = ((const float4*)wp)[k4];
      wreg[4 * k4 + 0] = v.x; wreg[4 * k4 + 1] = v.y;
      wreg[4 * k4 + 2] = v.z; wreg[4 * k4 + 3] = v.w;
    }
  }

  float c_reg = 0.f;
  float xgv = 0.f;
  int known = 0;                       // xg chunks known complete (wave0)
  if (w == 0) {
    while (__hip_atomic_load(&rdy32[0], __ATOMIC_RELAXED,
                             __HIP_MEMORY_SCOPE_AGENT) < 32) { }
    __threadfence();                   // acquire xg chunk 0
    known = 1;
    xgv = xg[grow];                    // x_gates[0][grow]
  }

  for (int t = 0; t < SEQ; ++t) {
    // Poll own h element: tag must equal t (tag+payload one atomic word).
    u64 word;
    const u64* src = hslot + (size_t)(t & (NSLOT - 1)) * HID + tid;
    do {
      word = __hip_atomic_load(src, __ATOMIC_RELAXED, __HIP_MEMORY_SCOPE_AGENT);
    } while ((unsigned)(word >> 32) != (unsigned)t);
    h_lds[tid] = __uint_as_float((unsigned)(word & 0xffffffffu));
    // No barrier: wave w reads only h_lds[64w..64w+63] (own lanes, lgkmcnt).

    const float* hb = &h_lds[w * 64];
    float p0 = 0.f, p1 = 0.f, p2 = 0.f, p3 = 0.f;
#pragma unroll
    for (int k = 0; k < 16; ++k) {
      p0 += wreg[k]      * hb[k];
      p1 += wreg[k + 16] * hb[k + 16];
      p2 += wreg[k + 32] * hb[k + 32];
      p3 += wreg[k + 48] * hb[k + 48];
    }
    part_lds[t & 1][w * 64 + l] = (p0 + p1) + (p2 + p3);
    __syncthreads();   // the only barrier per step

    if (w == 0) {
      const float* pp = &part_lds[t & 1][0];
      float s = ((pp[l]       + pp[64 + l])  + (pp[128 + l] + pp[192 + l]))
              + ((pp[256 + l] + pp[320 + l]) + (pp[384 + l] + pp[448 + l]));
      float gv = s + xgv;

      // Prefetch next step's xg (guard chunk readiness at crossings only).
      int tn = (t + 1 < SEQ) ? (t + 1) : (SEQ - 1);
      int nc = tn >> 5;
      if (nc >= known) {
        while (__hip_atomic_load(&rdy32[nc], __ATOMIC_RELAXED,
                                 __HIP_MEMORY_SCOPE_AGENT) < 32) { }
        __threadfence();
        known = nc + 1;
      }
      xgv = xg[(size_t)tn * G4 + grow];

      // Gather the 4 gate values for unit jj into lanes 0..15.
      float gi = __shfl(gv, jj,      64);
      float gf = __shfl(gv, jj + 16, 64);
      float gg = __shfl(gv, jj + 32, 64);
      float go = __shfl(gv, jj + 48, 64);

      if (l < UPB) {
        const float LOG2E = 1.442695041f;
        float i_ = 1.f / (1.f + __builtin_exp2f(-LOG2E * gi));
        float f_ = 1.f / (1.f + __builtin_exp2f(-LOG2E * gf));
        float g_ = 2.f / (1.f + __builtin_exp2f(-2.f * LOG2E * gg)) - 1.f;
        float o_ = 1.f / (1.f + __builtin_exp2f(-LOG2E * go));
        c_reg = f_ * c_reg + i_ * g_;
        float hv = o_ * (2.f / (1.f + __builtin_exp2f(-2.f * LOG2E * c_reg)) - 1.f);
        u64 outw = ((u64)(unsigned)(t + 1) << 32) | (u64)__float_as_uint(hv);
        __hip_atomic_store(hslot + (size_t)((t + 1) & (NSLOT - 1)) * HID + blk * UPB + jj,
                           outw, __ATOMIC_RELAXED, __HIP_MEMORY_SCOPE_AGENT);
      }
    }
  }

  // ============================ HEAD PHASE ============================
  // h^1024 lives in slot (1024 & 3) == 0 with tag 1024.
  {
    const u64* src = hslot + tid;
    u64 word;
    do {
      word = __hip_atomic_load(src, __ATOMIC_RELAXED, __HIP_MEMORY_SCOPE_AGENT);
    } while ((unsigned)(word >> 32) != (unsigned)SEQ);
    h_lds[tid] = __uint_as_float((unsigned)(word & 0xffffffffu));
    __syncthreads();

    const int vw   = tid >> 6;     // 0..7
    const int rsel = vw >> 2;      // 0/1
    const int row  = blk * 2 + rsel;
    const int k    = tid & 255;    // 0..255

    float p = attn_w[(size_t)row * HID + k]       * h_lds[k]
            + attn_w[(size_t)row * HID + 256 + k] * h_lds[256 + k];
#pragma unroll
    for (int off = 1; off < 64; off <<= 1) p += __shfl_xor(p, off, 64);
    if ((tid & 63) == 0) redh[vw] = p;
    __syncthreads();
    if (tid < 2) {
      float sum = redh[tid * 4] + redh[tid * 4 + 1]
                + redh[tid * 4 + 2] + redh[tid * 4 + 3] + attn_b[blk * 2 + tid];
      avals[tid] = 1.f / (1.f + __expf(-sum));
    }
    __syncthreads();

    float a = avals[rsel];
    ((float4*)(out + (size_t)row * 1024))[k] = make_float4(a, a, a, a);
    if (blk == 0) out[65536 + tid] = h_lds[tid];   // x_instr_rep = h
  }
}

// ---------------------------------------------------------------------------
extern "C" void kernel_launch(void* const* d_in, const int* in_sizes, int n_in,
                              void* d_out, int out_size, void* d_ws, size_t ws_size,
                              hipStream_t stream) {
  const int*   tok    = (const int*)  d_in[0];
  const float* emb    = (const float*)d_in[1];
  const float* w_ih   = (const float*)d_in[2];
  const float* w_hh   = (const float*)d_in[3];
  const float* b_ih   = (const float*)d_in[4];
  const float* b_hh   = (const float*)d_in[5];
  const float* attn_w = (const float*)d_in[6];
  const float* attn_b = (const float*)d_in[7];
  float* out = (float*)d_out;

  char* ws = (char*)d_ws;
  float* xg    = (float*)ws;                               // 8 MB
  u64*   hslot = (u64*)(ws + (size_t)SEQ * G4 * 4);        // 16 KB
  int*   rdy32 = (int*)(ws + (size_t)SEQ * G4 * 4 + NSLOT * HID * sizeof(u64));

  // Zero h slots (tag 0 == h^0 = 0) and the 32 chunk counters in one memset.
  hipMemsetAsync(hslot, 0, NSLOT * HID * sizeof(u64) + 32 * sizeof(int), stream);

  fused_kernel<<<NSCAN + NHELP, 512, 0, stream>>>(
      tok, emb, w_ih, w_hh, b_ih, b_hh, attn_w, attn_b, out, xg, hslot, rdy32);
}